// Round 13
// baseline (389.928 us; speedup 1.0000x reference)
//
#include <hip/hip_runtime.h>

#define N_PIX   (32 * 64 * 64)          // 131072 pixel rows
#define E_DIM   64
#define N_E     1024
#define Z_ELEMS (N_PIX * E_DIM)         // 8388608
#define TC      32                      // codes per LDS tile (8 KB)
#define NTL     16                      // tiles per code-half (512/32)
#define PPB     128                     // pixels per block (4 lanes/px, P=2)

#define LOSS_OFF 0
#define ZQ_OFF   1
#define PERP_OFF (1 + Z_ELEMS)                          // 8388609
#define ENC_OFF  ((size_t)(2 + Z_ELEMS))                // 8388610
#define IDX_OFF  (ENC_OFF + (size_t)N_PIX * N_E)        // 142606338

typedef float f32x2 __attribute__((ext_vector_type(2)));
typedef float f32x4 __attribute__((ext_vector_type(4)));
typedef unsigned long long u64;

// cross-lane adds within each 4-lane group (VALU pipe, no LDS traffic)
__device__ __forceinline__ float dpp_add_xor1(float v) {
    int i = __builtin_bit_cast(int, v);
    i = __builtin_amdgcn_mov_dpp(i, 0xB1, 0xF, 0xF, true);  // quad_perm(1,0,3,2)
    return v + __builtin_bit_cast(float, i);
}
__device__ __forceinline__ float dpp_add_xor2(float v) {
    int i = __builtin_bit_cast(int, v);
    i = __builtin_amdgcn_mov_dpp(i, 0x4E, 0xF, 0xF, true);  // quad_perm(2,3,0,1)
    return v + __builtin_bit_cast(float, i);
}

// ---- precompute ||e||^2 per codebook row ----
__global__ void vq_prep(const float* __restrict__ emb, float* __restrict__ ee) {
    int e = blockIdx.x * blockDim.x + threadIdx.x;
    if (e < N_E) {
        const float* r = emb + e * E_DIM;
        float s0 = 0.f, s1 = 0.f, s2 = 0.f, s3 = 0.f;
        #pragma unroll
        for (int c = 0; c < E_DIM; c += 4) {
            s0 = fmaf(r[c],     r[c],     s0);
            s1 = fmaf(r[c + 1], r[c + 1], s1);
            s2 = fmaf(r[c + 2], r[c + 2], s2);
            s3 = fmaf(r[c + 3], r[c + 3], s3);
        }
        ee[e] = (s0 + s1) + (s2 + s3);
    }
}

// ---- argmin kernel: split-K (2 blocks per 128-px group, 512 codes each) ----
// Frozen fp tree (R5/R9/R12). Merge across halves via atomicMin on
// key = (d_bits<<32)|idx: d = zz +- eps is strictly positive (zz ~ chi2_64
// >= ~20, |2 dot| <= 0.13) so float-bits ordering == float ordering, and
// lexicographic (d, idx) == np.argmin first-index semantics exactly.
// TC=32 + global_load_lds staging -> 16.4 KB LDS, ~60 VGPR, 8 blocks/CU.
__global__ __launch_bounds__(256, 8) void vq_argmin(
    const float* __restrict__ z, const float* __restrict__ emb,
    const float* __restrict__ ee, float* __restrict__ out,
    u64* __restrict__ keys)
{
    __shared__ float lds[2][TC * E_DIM];    // 2 x 8 KB

    const int tid   = threadIdx.x;
    const int h     = blockIdx.x & 1;        // code half: [0,512) or [512,1024)
    const int g     = blockIdx.x >> 1;       // pixel group
    const int s     = tid & 3;               // channel quarter 0..3
    const int pl    = tid >> 2;              // local pixel 0..63
    const int p0    = g * PPB + pl;          // pixels p0 and p0+64 (same image)
    const int b     = p0 >> 12;
    const int hw    = p0 & 4095;             // hw+64 stays < 4096
    const int cbase = h << 9;                // h*512

    // ---- my 16 channels of z for both pixels (stride 4096) ----
    const float* zp = z + ((size_t)b * E_DIM + s * 16) * 4096 + hw;
    f32x4 zv0[4], zv1[4];
    #pragma unroll
    for (int m = 0; m < 4; ++m) {
        #pragma unroll
        for (int q = 0; q < 4; ++q) {
            zv0[m][q] = zp[(size_t)(4 * m + q) * 4096];
            zv1[m][q] = zp[(size_t)(4 * m + q) * 4096 + 64];
        }
    }

    // ---- zz per pixel (frozen tree) ----
    float zz0, zz1;
    {
        f32x4 za = {0.f,0.f,0.f,0.f};
        #pragma unroll
        for (int j = 0; j < 4; ++j) za = __builtin_elementwise_fma(zv0[j], zv0[j], za);
        f32x2 zt = __builtin_shufflevector(za, za, 0, 1)
                 + __builtin_shufflevector(za, za, 2, 3);
        zz0 = dpp_add_xor2(dpp_add_xor1(zt.x + zt.y));
    }
    {
        f32x4 za = {0.f,0.f,0.f,0.f};
        #pragma unroll
        for (int j = 0; j < 4; ++j) za = __builtin_elementwise_fma(zv1[j], zv1[j], za);
        f32x2 zt = __builtin_shufflevector(za, za, 0, 1)
                 + __builtin_shufflevector(za, za, 2, 3);
        zz1 = dpp_add_xor2(dpp_add_xor1(zt.x + zt.y));
    }

    // ---- async staging: tile = 32 codes x 64 ch = 2048 floats; each wave
    // DMAs 2 chunks of 256 floats (global_load_lds, 16B/lane, linear) ----
    const int wid  = tid >> 6;
    const int lane = tid & 63;
    auto stage = [&](int t, int buf) {
        const float* gs = emb + (size_t)(cbase + t * TC) * E_DIM;
        #pragma unroll
        for (int j = 0; j < 2; ++j) {
            const int chunk = wid * 2 + j;
            auto gp = (const __attribute__((address_space(1))) float*)
                        (gs + chunk * 256 + lane * 4);
            auto lp = (__attribute__((address_space(3))) float*)
                        (&lds[buf][chunk * 256]);
            __builtin_amdgcn_global_load_lds(gp, lp, 16, 0, 0);
        }
    };

    stage(0, 0);
    __syncthreads();

    // one-hot zero stripe of this block: 128 rows x cols [h*512, h*512+512)
    const size_t zb = ENC_OFF + (size_t)g * PPB * N_E + (size_t)(h * 512);

    float dmin0 = 3.4e38f, dmin1 = 3.4e38f;
    int   best0 = 0, best1 = 0;

    for (int t = 0; t < NTL; ++t) {
        const int cur = t & 1;

        // streamed zero-fill (8 rows/tile, coalesced f32x2 NT; a full tile of
        // compute to retire before the next barrier waits on them)
        {
            const f32x2 zz_ = {0.f, 0.f};
            #pragma unroll
            for (int j = 0; j < 8; ++j)
                __builtin_nontemporal_store(zz_,
                    (f32x2*)(out + zb + (size_t)(t * 8 + j) * N_E + tid * 2));
        }
        if (t + 1 < NTL) stage(t + 1, cur ^ 1);   // async DMA, in flight over compute

        const f32x4* rows = (const f32x4*)lds[cur];
        const float* eet  = ee + cbase + t * TC;
        #pragma unroll 4
        for (int k = 0; k < TC; ++k) {
            f32x4 row[4];
            const f32x4* rp = rows + k * 16 + s * 4;   // my 16-ch quarter
            #pragma unroll
            for (int j = 0; j < 4; ++j) row[j] = rp[j];   // broadcast, 0-conflict

            // pixel 0 (frozen tree)
            {
                f32x4 a = {0.f,0.f,0.f,0.f};
                #pragma unroll
                for (int j = 0; j < 4; ++j) a = __builtin_elementwise_fma(zv0[j], row[j], a);
                f32x2 t2 = __builtin_shufflevector(a, a, 0, 1)
                         + __builtin_shufflevector(a, a, 2, 3);
                const float dot = dpp_add_xor2(dpp_add_xor1(t2.x + t2.y));
                const float d = zz0 + eet[k] - 2.0f * dot;
                if (d < dmin0) { dmin0 = d; best0 = cbase + t * TC + k; }
            }
            // pixel 1 (same tree)
            {
                f32x4 a = {0.f,0.f,0.f,0.f};
                #pragma unroll
                for (int j = 0; j < 4; ++j) a = __builtin_elementwise_fma(zv1[j], row[j], a);
                f32x2 t2 = __builtin_shufflevector(a, a, 0, 1)
                         + __builtin_shufflevector(a, a, 2, 3);
                const float dot = dpp_add_xor2(dpp_add_xor1(t2.x + t2.y));
                const float d = zz1 + eet[k] - 2.0f * dot;
                if (d < dmin1) { dmin1 = d; best1 = cbase + t * TC + k; }
            }
        }
        __syncthreads();   // waits the DMA (vmcnt) + LDS reads of this tile
    }

    // ---- publish per-half winners (quad-uniform; lane s==0 only) ----
    if (s == 0) {
        const u64 k0 = ((u64)__builtin_bit_cast(unsigned, dmin0) << 32) | (unsigned)best0;
        const u64 k1 = ((u64)__builtin_bit_cast(unsigned, dmin1) << 32) | (unsigned)best1;
        atomicMin(&keys[p0], k0);
        atomicMin(&keys[p0 + 64], k1);
    }
}

// ---- resolve: read merged keys -> idx, one-hot 1.0, z_q, loss, histogram ----
__global__ __launch_bounds__(256) void vq_resolve(
    const float* __restrict__ z, const float* __restrict__ emb,
    const u64* __restrict__ keys, float* __restrict__ out,
    unsigned* __restrict__ counts, double* __restrict__ loss_acc)
{
    const int p  = blockIdx.x * 256 + threadIdx.x;
    const int b  = p >> 12;
    const int hw = p & 4095;
    const int idx = (int)(unsigned)(keys[p] & 0xFFFFFFFFu);

    out[IDX_OFF + p] = (float)idx;
    out[ENC_OFF + (size_t)p * N_E + idx] = 1.0f;   // zeros already streamed
    atomicAdd(&counts[idx], 1u);

    const f32x4* eb = (const f32x4*)(emb + idx * E_DIM);
    const float* zp = z + (size_t)b * E_DIM * 4096 + hw;
    float* zqp = out + ZQ_OFF + (size_t)b * E_DIM * 4096 + hw;
    f32x4 la = {0.f,0.f,0.f,0.f};
    #pragma unroll
    for (int m = 0; m < 16; ++m) {
        const f32x4 q = eb[m];
        f32x4 zq4;
        #pragma unroll
        for (int qi = 0; qi < 4; ++qi) {
            zq4[qi] = zp[(size_t)(4 * m + qi) * 4096];
            __builtin_nontemporal_store(q[qi], &zqp[(size_t)(4 * m + qi) * 4096]);
        }
        const f32x4 dq = q - zq4;
        la = __builtin_elementwise_fma(dq, dq, la);
    }
    float lsum = (la[0] + la[2]) + (la[1] + la[3]);
    #pragma unroll
    for (int o = 32; o > 0; o >>= 1) lsum += __shfl_down(lsum, o);
    if ((threadIdx.x & 63) == 0) atomicAdd(loss_acc, (double)lsum);
}

// ---- finalize: perplexity + loss ----
__global__ void vq_final(const unsigned* __restrict__ counts,
                         const double* __restrict__ loss_acc,
                         float* __restrict__ out)
{
    __shared__ float red[N_E];
    const int e = threadIdx.x;
    const float em = (float)counts[e] * (1.0f / (float)N_PIX);
    red[e] = em * logf(em + 1e-10f);
    __syncthreads();
    for (int s = 512; s > 0; s >>= 1) {
        if (e < s) red[e] += red[e + s];
        __syncthreads();
    }
    if (e == 0) {
        out[PERP_OFF] = expf(-red[0]);
        out[LOSS_OFF] = (float)((*loss_acc) * (1.25 / (double)Z_ELEMS));
    }
}

extern "C" void kernel_launch(void* const* d_in, const int* in_sizes, int n_in,
                              void* d_out, int out_size, void* d_ws, size_t ws_size,
                              hipStream_t stream) {
    const float* z   = (const float*)d_in[0];
    const float* emb = (const float*)d_in[1];
    float* out = (float*)d_out;

    unsigned* counts   = (unsigned*)d_ws;                   // 4096 B
    double*   loss_acc = (double*)((char*)d_ws + 4096);     // 8 B
    float*    ee       = (float*)((char*)d_ws + 8192);      // 4096 B
    u64*      keys     = (u64*)((char*)d_ws + 16384);       // 1 MB

    (void)hipMemsetAsync(d_ws, 0, 4104, stream);
    (void)hipMemsetAsync(keys, 0xFF, (size_t)N_PIX * 8, stream);
    vq_prep<<<4, 256, 0, stream>>>(emb, ee);
    vq_argmin<<<2 * (N_PIX / PPB), 256, 0, stream>>>(z, emb, ee, out, keys);
    vq_resolve<<<N_PIX / 256, 256, 0, stream>>>(z, emb, keys, out, counts, loss_acc);
    vq_final<<<1, N_E, 0, stream>>>(counts, loss_acc, out);
}